// Round 8
// baseline (95.711 us; speedup 1.0000x reference)
//
#include <hip/hip_runtime.h>

#define NB   8
#define CIN  32
#define HH   28
#define WW   28
#define OC   64
#define HWSZ (HH*WW)            // 784
#define TOTAL (NB*OC*HWSZ)      // 401408
#define CNT  (NB*HWSZ)          // 6272 elements per channel

#define TROWS 6                 // rows h0-1 .. h0+4
#define TCOLS 30
#define TSZ   (CIN*TROWS*TCOLS) // 5760 floats = 23 KB LDS (reused for reduce)

#define CPW   4                 // oc per BLOCK (all 4 waves share the oc set)
#define QCC   8                 // input channels per wave (K split across 4 waves)
// grid: ocg(16) x rq(7) x n(8) = 896 blocks, 4 waves each

__global__ __launch_bounds__(256, 3) void adder_kernel(
    const float* __restrict__ x, const float* __restrict__ Wt,
    float* __restrict__ raw, double* __restrict__ stats)
{
    __shared__ float xs[TSZ];
    const int t   = threadIdx.x;
    const int bid = blockIdx.x;
    const int ocg = bid & 15;
    const int tmp = bid >> 4;
    const int rq  = tmp % 7;
    const int n   = tmp / 7;
    const int h0  = rq * 4;             // block covers output rows h0..h0+3
    const int o_base = ocg * CPW;

    // ---- stage x: all 32 channels, rows h0-1..h0+4, cols -1..28, zero-pad ----
    for (int i = t; i < TSZ; i += 256) {
        int cc  = i / (TROWS*TCOLS);
        int rem = i % (TROWS*TCOLS);
        int r   = rem / TCOLS;
        int col = rem % TCOLS;
        int hh  = h0 - 1 + r;
        int ww  = col - 1;
        float v = 0.0f;
        if (hh >= 0 && hh < HH && ww >= 0 && ww < WW)
            v = x[((n*CIN + cc)*HH + hh)*WW + ww];
        xs[i] = v;
    }
    __syncthreads();

    const int lane = t & 63;
    const int g    = __builtin_amdgcn_readfirstlane(t >> 6);  // wave = cc-quarter
    const int rg   = lane >> 5;         // row-pair within block (0,1)
    const int pl   = lane & 31;
    const bool valid = pl < WW;
    const int pw   = valid ? pl : 0;
    const int cbase = g * QCC;

    // ---- preload this wave's x quarter to VGPRs (one ds burst, one wait) ----
    float xr[QCC][4][3];                // 96 VGPRs
    #pragma unroll
    for (int cc = 0; cc < QCC; ++cc) {
        const int b0 = ((cbase+cc)*TROWS + 2*rg)*TCOLS + pw;
        #pragma unroll
        for (int dr = 0; dr < 4; ++dr)
            #pragma unroll
            for (int dc = 0; dc < 3; ++dc)
                xr[cc][dr][dc] = xs[b0 + dr*TCOLS + dc];
    }

    float acc[2][CPW];
    #pragma unroll
    for (int pix = 0; pix < 2; ++pix)
        #pragma unroll
        for (int oo = 0; oo < CPW; ++oo) acc[pix][oo] = 0.0f;

    // ---- steady state: pure wave-uniform W load + VALU, fully unrolled ----
    #pragma unroll
    for (int oo = 0; oo < CPW; ++oo) {
        const float* wp = Wt + ((o_base + oo)*CIN + cbase)*9;  // uniform
        #pragma unroll
        for (int cc = 0; cc < QCC; ++cc) {
            #pragma unroll
            for (int dr = 0; dr < 3; ++dr)
                #pragma unroll
                for (int dc = 0; dc < 3; ++dc) {
                    float w = wp[cc*9 + dr*3 + dc];
                    acc[0][oo] += __builtin_fabsf(xr[cc][dr][dc]   - w);
                    acc[1][oo] += __builtin_fabsf(xr[cc][dr+1][dc] - w);
                }
        }
    }

    // ---- cross-wave K reduction through LDS (reuse xs) ----
    __syncthreads();                    // everyone done reading xs
    float4* red = (float4*)xs;          // [3 waves][64 lanes][2 pix] float4
    if (g > 0) {
        const int base = ((g-1)*64 + lane)*2;
        red[base + 0] = *(float4*)&acc[0][0];
        red[base + 1] = *(float4*)&acc[1][0];
    }
    __syncthreads();
    if (g == 0) {
        #pragma unroll
        for (int w = 0; w < 3; ++w) {
            const int base = (w*64 + lane)*2;
            float4 a0 = red[base + 0];
            float4 a1 = red[base + 1];
            acc[0][0] += a0.x; acc[0][1] += a0.y; acc[0][2] += a0.z; acc[0][3] += a0.w;
            acc[1][0] += a1.x; acc[1][1] += a1.y; acc[1][2] += a1.z; acc[1][3] += a1.w;
        }

        // ---- write final conv output ----
        if (valid) {
            #pragma unroll
            for (int pix = 0; pix < 2; ++pix) {
                const int hh = h0 + 2*rg + pix;
                #pragma unroll
                for (int oo = 0; oo < CPW; ++oo)
                    raw[((n*OC + o_base + oo)*HH + hh)*WW + pw] = -acc[pix][oo];
            }
        }

        // ---- fused BN statistics: per-wave reduce, one atomic pair per oc ----
        #pragma unroll
        for (int oo = 0; oo < CPW; ++oo) {
            float v0 = valid ? -acc[0][oo] : 0.0f;
            float v1 = valid ? -acc[1][oo] : 0.0f;
            float s  = v0 + v1;
            float s2 = v0*v0 + v1*v1;
            #pragma unroll
            for (int off = 32; off >= 1; off >>= 1) {
                s  += __shfl_xor(s,  off, 64);
                s2 += __shfl_xor(s2, off, 64);
            }
            if (lane == 0) {
                atomicAdd(&stats[o_base + oo],      (double)s);
                atomicAdd(&stats[64 + o_base + oo], (double)s2);
            }
        }
    }
}

// y = raw*scale[o] + shift[o]; scale/shift computed inline from double stats
__global__ __launch_bounds__(256) void bn_kernel(
    const float* __restrict__ raw, const double* __restrict__ stats,
    const float* __restrict__ gamma, const float* __restrict__ beta,
    float* __restrict__ out)
{
    int i4 = blockIdx.x * 256 + threadIdx.x;   // float4 index
    if (i4 >= TOTAL/4) return;
    int o = (i4 / (HWSZ/4)) & (OC - 1);
    double mean = stats[o] * (1.0 / CNT);
    double var  = stats[64 + o] * (1.0 / CNT) - mean * mean;
    double inv  = 1.0 / sqrt(var + 1e-5);
    double scl  = (double)gamma[o] * inv;
    float s = (float)scl;
    float b = (float)((double)beta[o] - mean * scl);
    float4 a = ((const float4*)raw)[i4];
    float4 v;
    v.x = a.x * s + b;
    v.y = a.y * s + b;
    v.z = a.z * s + b;
    v.w = a.w * s + b;
    ((float4*)out)[i4] = v;
}

extern "C" void kernel_launch(void* const* d_in, const int* in_sizes, int n_in,
                              void* d_out, int out_size, void* d_ws, size_t ws_size,
                              hipStream_t stream) {
    const float* x     = (const float*)d_in[0];
    const float* Wt    = (const float*)d_in[1];
    const float* gamma = (const float*)d_in[2];
    const float* beta  = (const float*)d_in[3];
    float* out = (float*)d_out;

    // ws layout: [0,1024) stats (128 doubles); [4096, 4096+TOTAL*4) raw conv out
    double* stats = (double*)d_ws;
    float*  raw   = (float*)((char*)d_ws + 4096);

    hipMemsetAsync(d_ws, 0, 1024, stream);  // zero stats only (1 KB)

    adder_kernel<<<16*7*NB, 256, 0, stream>>>(x, Wt, raw, stats);
    bn_kernel<<<(TOTAL/4 + 255) / 256, 256, 0, stream>>>(raw, stats, gamma, beta, out);
}